// Round 11
// baseline (228.773 us; speedup 1.0000x reference)
//
#include <hip/hip_runtime.h>

// Problem constants (fixed by the reference)
constexpr int BN  = 64;          // batch
constexpr int HWP = 784;         // 28*28 spatial positions
constexpr int CQ  = 256;         // 1024 channels / 4 = float4s per position
constexpr float TAU = 0.5f / 784.0f;
constexpr float MS  = -(TAU / 7.0f);   // -beta*tau/n = -4*tau/28

// Native clang vector type (required by __builtin_nontemporal_store).
typedef float f32x4 __attribute__((ext_vector_type(4)));

__device__ __forceinline__ int iabs(int x) { return x < 0 ? -x : x; }

// ---------------------------------------------------------------------------
// One-tile-per-block fused kernel, pinned registers, FULL grid.
// Round-10 post-mortem: pin works (VGPR 60 = 52 data + 8 state, re-read
// eliminated) but dur was unchanged because the 512-block grid capped
// residency at 2 blocks/CU (occupancy 37%) — the machine can hold 4
// (VGPR 60 <= 64 -> 8 waves/SIMD; LDS 2.6 KB trivial). This round: same
// body, grid = 2048 one-tile blocks (round 4's grid + round 10's pin).
// More resident blocks = more phase diversity: some block is always in its
// load or store phase, covering the others' reduce stalls.
//
// Block bk = (batch b = bk>>5, 32-channel group cg = bk&31).
// Thread: q = t&7 (8 quads x 16 B = full 128 B line per position; round 5
// proved line-splitting doubles FETCH), s3 = t>>3; owns p = s3 + 64k,
// k=0..11, +k=12 if s3<16 (waves 0-1, wave-uniform tail).
// Argmax: per-lane strict '>' ascending p, then shfl_xor butterfly over the
// wave's 8 position-splits, then 8 wave-partials x 32 channels through
// 2.6 KB LDS, tie-break (v > bv) || (v == bv && x < bx) everywhere ->
// exact jnp.argmax first-occurrence semantics.
// Pin: asm "+v" after the argmax forces the 13 f32x4 to stay in VGPRs
// across both barriers (compiler cannot rematerialize the loads), so
// phase C is pure register->store: fabric 410 MB total (205 in + 205 out).
// Mask: tau * max(1 - 4d/28, -1) == max(fma(d, -tau/7, tau), -tau)
// (~2 ulp of tau; measured absmax 7.6e-6 vs threshold 6.9e-5).
// __launch_bounds__(512, 8): 8 waves/SIMD target -> VGPR cap 64 (body
// needs 60), 4 blocks/CU.
// ---------------------------------------------------------------------------
__global__ __launch_bounds__(512, 8) void fused_pin_full_kernel(
    const f32x4* __restrict__ in4, f32x4* __restrict__ out4) {
  __shared__ float s2v[8][32];
  __shared__ int   s2i[8][32];
  __shared__ int   s_peak[32];

  const int t  = threadIdx.x;
  const int q  = t & 7;           // channel quad within the 32-ch tile
  const int s3 = t >> 3;          // position split 0..63
  const int w  = t >> 6;          // wave 0..7
  const int b  = blockIdx.x >> 5;
  const int cg = blockIdx.x & 31;

  constexpr size_t KSTR = (size_t)64 * CQ;   // 64 positions per k-step
  const f32x4* sp = in4  + ((size_t)b * HWP + s3) * CQ + cg * 8 + q;
  f32x4*       dp = out4 + ((size_t)b * HWP + s3) * CQ + cg * 8 + q;

  const bool tail = (s3 < 16);    // wave-uniform (waves 0,1)
  const int  i0 = s3 / 28;
  const int  j0 = s3 - 28 * i0;
  const int  c0 = q * 4;

#define AMAX(vv, k) { const int p = s3 + 64 * (k); \
    if (vv.x > bm0) { bm0 = vv.x; bi0 = p; } \
    if (vv.y > bm1) { bm1 = vv.y; bi1 = p; } \
    if (vv.z > bm2) { bm2 = vv.z; bi2 = p; } \
    if (vv.w > bm3) { bm3 = vv.w; bi3 = p; } }

#define APK(vv, off) { f32x4 o; \
    o.x = vv.x * fmaxf(fmaf((float)(iabs(i - im0) + iabs(j - jm0)), MS, TAU), -TAU); \
    o.y = vv.y * fmaxf(fmaf((float)(iabs(i - im1) + iabs(j - jm1)), MS, TAU), -TAU); \
    o.z = vv.z * fmaxf(fmaf((float)(iabs(i - im2) + iabs(j - jm2)), MS, TAU), -TAU); \
    o.w = vv.w * fmaxf(fmaf((float)(iabs(i - im3) + iabs(j - jm3)), MS, TAU), -TAU); \
    __builtin_nontemporal_store(o, dp + (off)); \
    j += 8; i += 2; if (j >= 28) { j -= 28; ++i; } }   // p += 64

  // ---- Phase A: 12(+1) loads into named registers, per-lane argmax ----
  f32x4 v0  = sp[ 0 * KSTR], v1  = sp[ 1 * KSTR], v2  = sp[ 2 * KSTR];
  f32x4 v3  = sp[ 3 * KSTR], v4  = sp[ 4 * KSTR], v5  = sp[ 5 * KSTR];
  f32x4 v6  = sp[ 6 * KSTR], v7  = sp[ 7 * KSTR], v8  = sp[ 8 * KSTR];
  f32x4 v9  = sp[ 9 * KSTR], v10 = sp[10 * KSTR], v11 = sp[11 * KSTR];
  f32x4 vt  = {0.0f, 0.0f, 0.0f, 0.0f};
  if (tail) vt = sp[(size_t)12 * KSTR];

  float bm0 = -__builtin_inff(), bm1 = bm0, bm2 = bm0, bm3 = bm0;
  int   bi0 = s3, bi1 = s3, bi2 = s3, bi3 = s3;
  AMAX(v0, 0)  AMAX(v1, 1)  AMAX(v2, 2)  AMAX(v3, 3)
  AMAX(v4, 4)  AMAX(v5, 5)  AMAX(v6, 6)  AMAX(v7, 7)
  AMAX(v8, 8)  AMAX(v9, 9)  AMAX(v10, 10) AMAX(v11, 11)
  if (tail) {
    const int p = s3 + 768;
    if (vt.x > bm0) { bm0 = vt.x; bi0 = p; }
    if (vt.y > bm1) { bm1 = vt.y; bi1 = p; }
    if (vt.z > bm2) { bm2 = vt.z; bi2 = p; }
    if (vt.w > bm3) { bm3 = vt.w; bi3 = p; }
  }

  // ---- PIN: values must stay in VGPRs past the barriers (no re-load) ----
  asm volatile("" : "+v"(v0), "+v"(v1), "+v"(v2), "+v"(v3),
                    "+v"(v4), "+v"(v5), "+v"(v6), "+v"(v7),
                    "+v"(v8), "+v"(v9), "+v"(v10), "+v"(v11), "+v"(vt));

  // ---- In-wave butterfly over the 8 position sub-lanes ----
  #pragma unroll
  for (int st = 8; st < 64; st <<= 1) {
    { const float ov = __shfl_xor(bm0, st, 64); const int ox = __shfl_xor(bi0, st, 64);
      if (ov > bm0 || (ov == bm0 && ox < bi0)) { bm0 = ov; bi0 = ox; } }
    { const float ov = __shfl_xor(bm1, st, 64); const int ox = __shfl_xor(bi1, st, 64);
      if (ov > bm1 || (ov == bm1 && ox < bi1)) { bm1 = ov; bi1 = ox; } }
    { const float ov = __shfl_xor(bm2, st, 64); const int ox = __shfl_xor(bi2, st, 64);
      if (ov > bm2 || (ov == bm2 && ox < bi2)) { bm2 = ov; bi2 = ox; } }
    { const float ov = __shfl_xor(bm3, st, 64); const int ox = __shfl_xor(bi3, st, 64);
      if (ov > bm3 || (ov == bm3 && ox < bi3)) { bm3 = ov; bi3 = ox; } }
  }

  // ---- Cross-wave reduce via tiny LDS ----
  if ((t & 56) == 0) {            // one rep lane per (wave, quad)
    s2v[w][c0 + 0] = bm0; s2i[w][c0 + 0] = bi0;
    s2v[w][c0 + 1] = bm1; s2i[w][c0 + 1] = bi1;
    s2v[w][c0 + 2] = bm2; s2i[w][c0 + 2] = bi2;
    s2v[w][c0 + 3] = bm3; s2i[w][c0 + 3] = bi3;
  }
  __syncthreads();
  if (t < 32) {
    float bv = s2v[0][t];
    int   bx = s2i[0][t];
    #pragma unroll
    for (int g = 1; g < 8; ++g) {
      const float vv = s2v[g][t];
      const int   xx = s2i[g][t];
      if (vv > bv || (vv == bv && xx < bx)) { bv = vv; bx = xx; }
    }
    const int im = bx / 28;
    s_peak[t] = (im << 8) | (bx - 28 * im);
  }
  __syncthreads();

  // ---- Phase C: mask the register-resident values, nontemporal store ----
  const int pk0 = s_peak[c0 + 0], pk1 = s_peak[c0 + 1];
  const int pk2 = s_peak[c0 + 2], pk3 = s_peak[c0 + 3];
  const int im0 = pk0 >> 8, jm0 = pk0 & 255;
  const int im1 = pk1 >> 8, jm1 = pk1 & 255;
  const int im2 = pk2 >> 8, jm2 = pk2 & 255;
  const int im3 = pk3 >> 8, jm3 = pk3 & 255;

  int i = i0, j = j0;
  APK(v0,  0 * KSTR) APK(v1,  1 * KSTR) APK(v2,  2 * KSTR)
  APK(v3,  3 * KSTR) APK(v4,  4 * KSTR) APK(v5,  5 * KSTR)
  APK(v6,  6 * KSTR) APK(v7,  7 * KSTR) APK(v8,  8 * KSTR)
  APK(v9,  9 * KSTR) APK(v10, 10 * KSTR) APK(v11, 11 * KSTR)
  if (tail) {
    f32x4 o;
    o.x = vt.x * fmaxf(fmaf((float)(iabs(i - im0) + iabs(j - jm0)), MS, TAU), -TAU);
    o.y = vt.y * fmaxf(fmaf((float)(iabs(i - im1) + iabs(j - jm1)), MS, TAU), -TAU);
    o.z = vt.z * fmaxf(fmaf((float)(iabs(i - im2) + iabs(j - jm2)), MS, TAU), -TAU);
    o.w = vt.w * fmaxf(fmaf((float)(iabs(i - im3) + iabs(j - jm3)), MS, TAU), -TAU);
    __builtin_nontemporal_store(o, dp + (size_t)12 * KSTR);
  }
#undef APK
#undef AMAX
}

extern "C" void kernel_launch(void* const* d_in, const int* in_sizes, int n_in,
                              void* d_out, int out_size, void* d_ws, size_t ws_size,
                              hipStream_t stream) {
  const f32x4* in4  = (const f32x4*)d_in[0];
  f32x4*       out4 = (f32x4*)d_out;
  // One block per (batch, 32-channel group): 64 x 32 = 2048 blocks, 512 thr,
  // 4 blocks/CU resident (VGPR 60 <= 64).
  fused_pin_full_kernel<<<BN * 32, 512, 0, stream>>>(in4, out4);
}

// Round 12
// 69.878 us; speedup vs baseline: 3.2739x; 3.2739x over previous
//
#include <hip/hip_runtime.h>

// Problem constants (fixed by the reference)
constexpr int BN  = 64;          // batch
constexpr int HWP = 784;         // 28*28 spatial positions
constexpr int CQ  = 256;         // 1024 channels / 4 = float4s per position
constexpr float TAU = 0.5f / 784.0f;
constexpr float MS  = -(TAU / 7.0f);   // -beta*tau/n = -4*tau/28

// Native clang vector type (required by __builtin_nontemporal_store).
typedef float f32x4 __attribute__((ext_vector_type(4)));

__device__ __forceinline__ int iabs(int x) { return x < 0 ? -x : x; }

// ---------------------------------------------------------------------------
// One-tile-per-block fused kernel, pinned registers, full grid.
// Round-11 lesson: __launch_bounds__(512,8) capped VGPR at 32 -> the pinned
// 52 data registers spilled to scratch (FETCH 279 GB, WRITE 633 GB, 256 us).
// Round-10 build with (512,4) compiled to VGPR=60, which ALREADY permits
// 8 waves/SIMD (halving threshold 64) — the tighter bound was never needed.
// This round: (512,4) + 2048-block grid = pin x full residency.
//
// Block bk = (batch b = bk>>5, 32-channel group cg = bk&31).
// Thread: q = t&7 (8 quads x 16 B = full 128 B line per position; round 5
// proved line-splitting doubles FETCH), s3 = t>>3; owns p = s3 + 64k,
// k=0..11, +k=12 if s3<16 (waves 0-1, wave-uniform tail).
// Argmax: per-lane strict '>' ascending p, then shfl_xor butterfly over the
// wave's 8 position-splits, then 8 wave-partials x 32 channels through
// 2.6 KB LDS, tie-break (v > bv) || (v == bv && x < bx) everywhere ->
// exact jnp.argmax first-occurrence semantics.
// Pin: asm "+v" after the argmax forces the 13 f32x4 to stay in VGPRs
// across both barriers (no rematerialized re-read in phase C): fabric
// traffic 410 MB total (205 in + 205 out), verified round 10 (VGPR 60,
// FETCH 100 GB-units).
// Mask: tau * max(1 - 4d/28, -1) == max(fma(d, -tau/7, tau), -tau)
// (~2 ulp of tau; measured absmax 7.6e-6 vs threshold 6.9e-5).
// ---------------------------------------------------------------------------
__global__ __launch_bounds__(512, 4) void fused_pin_full_kernel(
    const f32x4* __restrict__ in4, f32x4* __restrict__ out4) {
  __shared__ float s2v[8][32];
  __shared__ int   s2i[8][32];
  __shared__ int   s_peak[32];

  const int t  = threadIdx.x;
  const int q  = t & 7;           // channel quad within the 32-ch tile
  const int s3 = t >> 3;          // position split 0..63
  const int w  = t >> 6;          // wave 0..7
  const int b  = blockIdx.x >> 5;
  const int cg = blockIdx.x & 31;

  constexpr size_t KSTR = (size_t)64 * CQ;   // 64 positions per k-step
  const f32x4* sp = in4  + ((size_t)b * HWP + s3) * CQ + cg * 8 + q;
  f32x4*       dp = out4 + ((size_t)b * HWP + s3) * CQ + cg * 8 + q;

  const bool tail = (s3 < 16);    // wave-uniform (waves 0,1)
  const int  i0 = s3 / 28;
  const int  j0 = s3 - 28 * i0;
  const int  c0 = q * 4;

#define AMAX(vv, k) { const int p = s3 + 64 * (k); \
    if (vv.x > bm0) { bm0 = vv.x; bi0 = p; } \
    if (vv.y > bm1) { bm1 = vv.y; bi1 = p; } \
    if (vv.z > bm2) { bm2 = vv.z; bi2 = p; } \
    if (vv.w > bm3) { bm3 = vv.w; bi3 = p; } }

#define APK(vv, off) { f32x4 o; \
    o.x = vv.x * fmaxf(fmaf((float)(iabs(i - im0) + iabs(j - jm0)), MS, TAU), -TAU); \
    o.y = vv.y * fmaxf(fmaf((float)(iabs(i - im1) + iabs(j - jm1)), MS, TAU), -TAU); \
    o.z = vv.z * fmaxf(fmaf((float)(iabs(i - im2) + iabs(j - jm2)), MS, TAU), -TAU); \
    o.w = vv.w * fmaxf(fmaf((float)(iabs(i - im3) + iabs(j - jm3)), MS, TAU), -TAU); \
    __builtin_nontemporal_store(o, dp + (off)); \
    j += 8; i += 2; if (j >= 28) { j -= 28; ++i; } }   // p += 64

  // ---- Phase A: 12(+1) loads into named registers, per-lane argmax ----
  f32x4 v0  = sp[ 0 * KSTR], v1  = sp[ 1 * KSTR], v2  = sp[ 2 * KSTR];
  f32x4 v3  = sp[ 3 * KSTR], v4  = sp[ 4 * KSTR], v5  = sp[ 5 * KSTR];
  f32x4 v6  = sp[ 6 * KSTR], v7  = sp[ 7 * KSTR], v8  = sp[ 8 * KSTR];
  f32x4 v9  = sp[ 9 * KSTR], v10 = sp[10 * KSTR], v11 = sp[11 * KSTR];
  f32x4 vt  = {0.0f, 0.0f, 0.0f, 0.0f};
  if (tail) vt = sp[(size_t)12 * KSTR];

  float bm0 = -__builtin_inff(), bm1 = bm0, bm2 = bm0, bm3 = bm0;
  int   bi0 = s3, bi1 = s3, bi2 = s3, bi3 = s3;
  AMAX(v0, 0)  AMAX(v1, 1)  AMAX(v2, 2)  AMAX(v3, 3)
  AMAX(v4, 4)  AMAX(v5, 5)  AMAX(v6, 6)  AMAX(v7, 7)
  AMAX(v8, 8)  AMAX(v9, 9)  AMAX(v10, 10) AMAX(v11, 11)
  if (tail) {
    const int p = s3 + 768;
    if (vt.x > bm0) { bm0 = vt.x; bi0 = p; }
    if (vt.y > bm1) { bm1 = vt.y; bi1 = p; }
    if (vt.z > bm2) { bm2 = vt.z; bi2 = p; }
    if (vt.w > bm3) { bm3 = vt.w; bi3 = p; }
  }

  // ---- PIN: values must stay in VGPRs past the barriers (no re-load) ----
  asm volatile("" : "+v"(v0), "+v"(v1), "+v"(v2), "+v"(v3),
                    "+v"(v4), "+v"(v5), "+v"(v6), "+v"(v7),
                    "+v"(v8), "+v"(v9), "+v"(v10), "+v"(v11), "+v"(vt));

  // ---- In-wave butterfly over the 8 position sub-lanes ----
  #pragma unroll
  for (int st = 8; st < 64; st <<= 1) {
    { const float ov = __shfl_xor(bm0, st, 64); const int ox = __shfl_xor(bi0, st, 64);
      if (ov > bm0 || (ov == bm0 && ox < bi0)) { bm0 = ov; bi0 = ox; } }
    { const float ov = __shfl_xor(bm1, st, 64); const int ox = __shfl_xor(bi1, st, 64);
      if (ov > bm1 || (ov == bm1 && ox < bi1)) { bm1 = ov; bi1 = ox; } }
    { const float ov = __shfl_xor(bm2, st, 64); const int ox = __shfl_xor(bi2, st, 64);
      if (ov > bm2 || (ov == bm2 && ox < bi2)) { bm2 = ov; bi2 = ox; } }
    { const float ov = __shfl_xor(bm3, st, 64); const int ox = __shfl_xor(bi3, st, 64);
      if (ov > bm3 || (ov == bm3 && ox < bi3)) { bm3 = ov; bi3 = ox; } }
  }

  // ---- Cross-wave reduce via tiny LDS ----
  if ((t & 56) == 0) {            // one rep lane per (wave, quad)
    s2v[w][c0 + 0] = bm0; s2i[w][c0 + 0] = bi0;
    s2v[w][c0 + 1] = bm1; s2i[w][c0 + 1] = bi1;
    s2v[w][c0 + 2] = bm2; s2i[w][c0 + 2] = bi2;
    s2v[w][c0 + 3] = bm3; s2i[w][c0 + 3] = bi3;
  }
  __syncthreads();
  if (t < 32) {
    float bv = s2v[0][t];
    int   bx = s2i[0][t];
    #pragma unroll
    for (int g = 1; g < 8; ++g) {
      const float vv = s2v[g][t];
      const int   xx = s2i[g][t];
      if (vv > bv || (vv == bv && xx < bx)) { bv = vv; bx = xx; }
    }
    const int im = bx / 28;
    s_peak[t] = (im << 8) | (bx - 28 * im);
  }
  __syncthreads();

  // ---- Phase C: mask the register-resident values, nontemporal store ----
  const int pk0 = s_peak[c0 + 0], pk1 = s_peak[c0 + 1];
  const int pk2 = s_peak[c0 + 2], pk3 = s_peak[c0 + 3];
  const int im0 = pk0 >> 8, jm0 = pk0 & 255;
  const int im1 = pk1 >> 8, jm1 = pk1 & 255;
  const int im2 = pk2 >> 8, jm2 = pk2 & 255;
  const int im3 = pk3 >> 8, jm3 = pk3 & 255;

  int i = i0, j = j0;
  APK(v0,  0 * KSTR) APK(v1,  1 * KSTR) APK(v2,  2 * KSTR)
  APK(v3,  3 * KSTR) APK(v4,  4 * KSTR) APK(v5,  5 * KSTR)
  APK(v6,  6 * KSTR) APK(v7,  7 * KSTR) APK(v8,  8 * KSTR)
  APK(v9,  9 * KSTR) APK(v10, 10 * KSTR) APK(v11, 11 * KSTR)
  if (tail) {
    f32x4 o;
    o.x = vt.x * fmaxf(fmaf((float)(iabs(i - im0) + iabs(j - jm0)), MS, TAU), -TAU);
    o.y = vt.y * fmaxf(fmaf((float)(iabs(i - im1) + iabs(j - jm1)), MS, TAU), -TAU);
    o.z = vt.z * fmaxf(fmaf((float)(iabs(i - im2) + iabs(j - jm2)), MS, TAU), -TAU);
    o.w = vt.w * fmaxf(fmaf((float)(iabs(i - im3) + iabs(j - jm3)), MS, TAU), -TAU);
    __builtin_nontemporal_store(o, dp + (size_t)12 * KSTR);
  }
#undef APK
#undef AMAX
}

extern "C" void kernel_launch(void* const* d_in, const int* in_sizes, int n_in,
                              void* d_out, int out_size, void* d_ws, size_t ws_size,
                              hipStream_t stream) {
  const f32x4* in4  = (const f32x4*)d_in[0];
  f32x4*       out4 = (f32x4*)d_out;
  // One block per (batch, 32-channel group): 64 x 32 = 2048 blocks, 512 thr.
  // VGPR=60 (round-10 measurement) <= 64 -> HW can hold 4 blocks/CU.
  fused_pin_full_kernel<<<BN * 32, 512, 0, stream>>>(in4, out4);
}